// Round 11
// baseline (162.955 us; speedup 1.0000x reference)
//
#include <hip/hip_runtime.h>
#include <hip/hip_bf16.h>

// ---------- types ----------
typedef __attribute__((ext_vector_type(8))) short short8;      // 8 x bf16 (4 VGPR) MFMA frag
typedef __attribute__((ext_vector_type(4))) float f32x4;       // MFMA accumulator
typedef __attribute__((ext_vector_type(4))) unsigned short u16x4;

// ---------- constants ----------
#define NB 4
#define NN 1024
#define NC 768
#define NH 12
#define TC 2304

// workspace byte offsets
#define OFF_XB   0ul
#define OFF_WQ   6291456ul
#define OFF_WMU  (OFF_WQ + 3538944ul)
#define OFF_WLS  (OFF_WMU + 589824ul)
#define OFF_QKVB (OFF_WLS + 589824ul)
#define OFF_V3   (OFF_QKVB + 18874368ul)
#define OFF_OUTB (OFF_V3 + 6291456ul)

__device__ __forceinline__ unsigned short f2bf(float f) {
    unsigned int u = __float_as_uint(f);
    u = (u + 0x7FFFu + ((u >> 16) & 1u)) >> 16;
    return (unsigned short)u;
}

__device__ __forceinline__ void gload_lds16(const unsigned short* g, unsigned short* l) {
    __builtin_amdgcn_global_load_lds(
        (const __attribute__((address_space(1))) unsigned int*)g,
        (__attribute__((address_space(3))) unsigned int*)l, 16, 0, 0);
}

__device__ __forceinline__ void gload16(short8& dst, const unsigned short* p) {
    asm volatile("global_load_dwordx4 %0, %1, off" : "=v"(dst) : "v"(p));
}
#define WAITV(N) do { asm volatile("s_waitcnt vmcnt(" #N ")" ::: "memory"); \
                      __builtin_amdgcn_sched_barrier(0); } while (0)
#define SBAR()   __builtin_amdgcn_sched_barrier(0)

// ---------- fused cast f32 -> bf16 ----------
__global__ void cast_all(const float* __restrict__ x, const float* __restrict__ qkv_w,
                         const float* __restrict__ mu_w, const float* __restrict__ ls_w,
                         unsigned short* __restrict__ dst) {
    int i = blockIdx.x * blockDim.x + threadIdx.x;
    const float* src; int off;
    if (i < 786432)            { src = x;     off = i; }
    else if (i < 1228800)      { src = qkv_w; off = i - 786432; }
    else if (i < 1302528)      { src = mu_w;  off = i - 1228800; }
    else                       { src = ls_w;  off = i - 1302528; }
    f32x4 v = ((const f32x4*)src)[off];
    u16x4 o;
#pragma unroll
    for (int j = 0; j < 4; ++j) o[j] = f2bf(v[j]);
    ((u16x4*)dst)[i] = o;
}

// ---------- shared GEMM body (validated) ----------
template <int EPI>
__device__ __forceinline__ void gemm_body(
    unsigned short* As, unsigned short* Bs,
    const unsigned short* __restrict__ A, const unsigned short* __restrict__ Bm,
    int K, int lda, int ldb, void* __restrict__ Cout, int ldc,
    const float* __restrict__ bias, int row0, int col0)
{
    const int t = threadIdx.x;
    const int lane = t & 63;
    const int wv = t >> 6;
    const int wm = wv >> 1, wn = wv & 1;
    const int li = lane & 15;
    const int koff = (lane >> 4) * 8;

    f32x4 acc[4][4] = {};

    const int tr = t >> 2;
    const int tc = (t & 3) * 8;
    const unsigned short* ag = A + (size_t)(row0 + tr) * lda + tc;
    const unsigned short* bg = Bm + (size_t)(col0 + tr) * ldb + tc;

    for (int kt = 0; kt < K; kt += 32) {
        gload_lds16(ag,            As + t * 8);
        gload_lds16(ag + 64 * lda, As + 2048 + t * 8);
        gload_lds16(bg,            Bs + t * 8);
        gload_lds16(bg + 64 * ldb, Bs + 2048 + t * 8);
        ag += 32; bg += 32;
        __syncthreads();
        short8 af[4], bf[4];
#pragma unroll
        for (int m = 0; m < 4; ++m)
            af[m] = *(const short8*)&As[(wm * 64 + m * 16 + li) * 32 + koff];
#pragma unroll
        for (int n = 0; n < 4; ++n)
            bf[n] = *(const short8*)&Bs[(wn * 64 + n * 16 + li) * 32 + koff];
#pragma unroll
        for (int m = 0; m < 4; ++m)
#pragma unroll
            for (int n = 0; n < 4; ++n)
                acc[m][n] = __builtin_amdgcn_mfma_f32_16x16x32_bf16(af[m], bf[n], acc[m][n], 0, 0, 0);
        __syncthreads();
    }

#pragma unroll
    for (int m = 0; m < 4; ++m) {
        const int row = row0 + wm * 64 + m * 16 + (lane >> 4) * 4;
#pragma unroll
        for (int n = 0; n < 4; ++n) {
            const int col = col0 + wn * 64 + n * 16 + li;
#pragma unroll
            for (int r = 0; r < 4; ++r) {
                if (EPI == 0) {
                    ((unsigned short*)Cout)[(size_t)(row + r) * ldc + col] = f2bf(acc[m][n][r]);
                } else {
                    ((float*)Cout)[(size_t)(row + r) * ldc + col] = acc[m][n][r] + bias[col];
                }
            }
        }
    }
}

__global__ __launch_bounds__(256, 2) void gemm_qkv(
    const unsigned short* __restrict__ A, const unsigned short* __restrict__ Bm,
    unsigned short* __restrict__ C)
{
    __shared__ unsigned short As[128 * 32];
    __shared__ unsigned short Bs[128 * 32];
    const int bid = blockIdx.y * gridDim.x + blockIdx.x;
    const int nwg = gridDim.x * gridDim.y;
    const int swz = (bid & 7) * (nwg >> 3) + (bid >> 3);
    const int row0 = (swz / gridDim.x) * 128;
    const int col0 = (swz % gridDim.x) * 128;
    gemm_body<0>(As, Bs, A, Bm, NC, NC, NC, C, TC, nullptr, row0, col0);
}

__global__ __launch_bounds__(256, 2) void gemm_heads(
    const unsigned short* __restrict__ outb,
    const unsigned short* __restrict__ wmu, const unsigned short* __restrict__ wls,
    const float* __restrict__ mu_b, const float* __restrict__ ls_b,
    float* __restrict__ out_mu, float* __restrict__ out_ls)
{
    __shared__ unsigned short As[128 * 32];
    __shared__ unsigned short Bs[128 * 32];
    const int bid = blockIdx.y * gridDim.x + blockIdx.x;
    const int nwg = gridDim.x * gridDim.y;
    const int swz = (bid & 7) * (nwg >> 3) + (bid >> 3);
    const int row0 = (swz / gridDim.x) * 128;
    const int col0 = (swz % gridDim.x) * 128;
    const int z = blockIdx.z;
    gemm_body<1>(As, Bs, outb + (z ? 384 : 0), z ? wls : wmu, 384, NC, 384,
                 z ? (void*)out_ls : (void*)out_mu, NC, z ? ls_b : mu_b, row0, col0);
}

// ---------- pack V only (frag-order): v3[bh][kt=m/32][d][m%32] ----------
__global__ __launch_bounds__(256, 4) void pack_v(
    const unsigned short* __restrict__ qkvb, unsigned short* __restrict__ v3)
{
    __shared__ unsigned short tile[64][65];
    const int t = threadIdx.x;
    const int bh = blockIdx.y;
    const int b = bh / NH, h = bh % NH;
    const int m0 = blockIdx.x * 64;
#pragma unroll
    for (int i = 0; i < 2; ++i) {
        int lin = i * 256 + t;
        int mr = lin >> 3;
        int dr = (lin & 7) * 8;
        short8 v = *(const short8*)(qkvb + (size_t)(b * NN + m0 + mr) * TC + 1536 + h * 64 + dr);
#pragma unroll
        for (int j = 0; j < 8; ++j) tile[mr][dr + j] = (unsigned short)v[j];
    }
    __syncthreads();
#pragma unroll
    for (int i = 0; i < 2; ++i) {
        int lin = i * 256 + t;
        int dw = lin >> 3;
        int mw = (lin & 7) * 8;
        short8 v;
#pragma unroll
        for (int j = 0; j < 8; ++j) v[j] = (short)tile[mw + j][dw];
        int kt = (m0 + mw) >> 5;
        int mm = mw & 31;
        *(short8*)(v3 + ((size_t)(bh * 32 + kt) * 64 + dw) * 32 + mm) = v;
    }
}

// ---------- fused attention: QBLK=32, 256-key cooperative chunks, setprio, deep PV ----------
// grid (32, 48); block 512 = 8 waves. QK: wave (qs = wv>>2, ke = wv&3) covers
// q-subtile qs (16 rows) x key-64-slice ke of each cooperative 256-key chunk.
__global__ __launch_bounds__(512, 2) void attn_kernel(
    const unsigned short* __restrict__ qkvb, const unsigned short* __restrict__ v3,
    const float* __restrict__ mask, const float* __restrict__ weight,
    float* __restrict__ attn_out, unsigned short* __restrict__ outb)
{
    __shared__ __align__(16) char smem[66048];   // K dbuf 2x32KB | later P[32][1032]
    __shared__ f32x4 po[4][2][64];               // PV k-half exchange
    __shared__ float red_max[8][16];
    __shared__ float red_sum[8][16];

    const int t = threadIdx.x;
    const int lane = t & 63;
    const int wv = t >> 6;                 // 0..7
    const int li = lane & 15;
    const int g = lane >> 4;
    const int koff = g * 8;
    const int bh = blockIdx.y;
    const int b = bh / NH, h = bh % NH;
    const int n0 = blockIdx.x * 32;
    const int qs = wv >> 2;                // q-subtile 0..1
    const int ke = wv & 3;                 // key-64-slice 0..3

    unsigned short* sm = (unsigned short*)smem;

    // q frags (B-operand): col = li -> q-row n0+qs*16+li
    const unsigned short* qp = qkvb + (size_t)(b * NN + n0 + qs * 16 + li) * TC + h * 64 + koff;
    short8 qf0 = *(const short8*)qp;
    short8 qf1 = *(const short8*)(qp + 32);

    // weight: lane l = ck*16 + s*4 + g holds cols ck*256 + ke*64 + s*16 + g*4 ..+4
    f32x4 w4 = *(const f32x4*)(weight + b * NN + (lane >> 4) * 256 + ke * 64 + (lane & 15) * 4);

    const float* mrow = mask + (size_t)b * NN * NN + (size_t)(n0 + qs * 16 + li) * NN
                      + ke * 64 + g * 4;

    const unsigned short* kgbase = qkvb + (size_t)(b * NN) * TC + 768 + h * 64;

    f32x4 acc[16];
    f32x4 mk[2][4];

    // cooperative stage of 256-key chunk ck into buf ck&1 (4 gload_lds/wave, 1KB each).
    // LDS dest: uniform base + lane*16. Source slot pre-XOR'd (both-sides swizzle rule).
    auto stage = [&](int ck) {
#pragma unroll
        for (int i = 0; i < 4; ++i) {
            int m = wv * 32 + i * 8 + (lane >> 3);        // key within chunk 0..255
            int sl = (lane & 7) ^ (m & 7);                // swizzled 16B slot in source
            const unsigned short* src = kgbase + (size_t)(ck * 256 + m) * TC + sl * 8;
            unsigned short* dst = sm + (ck & 1) * 16384 + wv * 2048 + i * 512 + lane * 8;
            gload_lds16(src, dst);
        }
    };
    auto mload = [&](int ck) {
#pragma unroll
        for (int s = 0; s < 4; ++s)
            mk[ck & 1][s] = *(const f32x4*)(mrow + ck * 256 + s * 16);
    };

    stage(0);
    mload(0);
    __syncthreads();                        // drains stage(0)+mk[0]

#pragma unroll
    for (int ck = 0; ck < 4; ++ck) {
        if (ck < 3) { stage(ck + 1); mload(ck + 1); }
        const unsigned short* kbuf = sm + (ck & 1) * 16384;
        __builtin_amdgcn_s_setprio(1);
#pragma unroll
        for (int s = 0; s < 4; ++s) {
            const int m = ke * 64 + s * 16 + li;          // key within chunk (frag row)
            short8 kf0 = *(const short8*)&kbuf[m * 64 + ((g ^ (m & 7)) * 8)];
            short8 kf1 = *(const short8*)&kbuf[m * 64 + (((g + 4) ^ (m & 7)) * 8)];
            f32x4 ci = mk[ck & 1][s] * 96.0f;             // mask as C-in (scale=1/96 exact)
            ci = __builtin_amdgcn_mfma_f32_16x16x32_bf16(kf0, qf0, ci, 0, 0, 0);
            ci = __builtin_amdgcn_mfma_f32_16x16x32_bf16(kf1, qf1, ci, 0, 0, 0);
            acc[ck * 4 + s] = ci;
        }
        __builtin_amdgcn_s_setprio(0);
        __syncthreads();                    // staging of ck+1 complete; buf reuse safe
    }

    // ---- row max (acc = s*96; monotone)
    const float scale = 1.0f / 96.0f;
    float rmax = -1e30f;
#pragma unroll
    for (int cf = 0; cf < 16; ++cf) {
#pragma unroll
        for (int r = 0; r < 4; ++r) rmax = fmaxf(rmax, acc[cf][r]);
    }
    rmax = fmaxf(rmax, __shfl_xor(rmax, 16, 64));
    rmax = fmaxf(rmax, __shfl_xor(rmax, 32, 64));
    if (lane < 16) red_max[wv][lane] = rmax;
    __syncthreads();
    rmax = fmaxf(fmaxf(red_max[qs * 4 + 0][li], red_max[qs * 4 + 1][li]),
                 fmaxf(red_max[qs * 4 + 2][li], red_max[qs * 4 + 3][li])) * scale;

    // ---- p = exp(s-max)*w; stage bf16 p into P (overlays K bufs); weighted row sum
    unsigned short (*P)[1032] = (unsigned short(*)[1032])smem;
    float rsum = 0.f;
#pragma unroll
    for (int cf = 0; cf < 16; ++cf) {       // cf = ck*4+s
        f32x4 wcf;
#pragma unroll
        for (int r = 0; r < 4; ++r) wcf[r] = __shfl(w4[r], cf * 4 + g, 64);
        u16x4 pb;
#pragma unroll
        for (int r = 0; r < 4; ++r) {
            float p = __expf(acc[cf][r] * scale - rmax) * (wcf[r] + 1e-10f);
            acc[cf][r] = p;
            rsum += p;
            pb[r] = f2bf(p);
        }
        const int col = (cf >> 2) * 256 + ke * 64 + (cf & 3) * 16 + g * 4;
        *(u16x4*)&P[qs * 16 + li][col] = pb;
    }
    rsum += __shfl_xor(rsum, 16, 64);
    rsum += __shfl_xor(rsum, 32, 64);
    if (lane < 16) red_sum[wv][lane] = rsum;
    __syncthreads();                        // P complete + red_sum ready

    // ---- PV: wave (kh = wv>>2, p4 = wv&3): keys [kh*512,+512), d-cols [p4*16,+16),
    //      both q-subtiles share each V frag. All 16 V loads upfront, countdown waits.
    const int kh = wv >> 2, p4 = wv & 3;
    f32x4 o0 = {}, o1 = {};
    const unsigned short* v3s = v3 + (size_t)bh * 65536 + (size_t)(kh * 16) * 2048
                              + p4 * 512 + li * 32 + g * 8;
    short8 vA[4], vB[4], vC[4], vD[4];
#define VISSUE(c, vb2) do {                                                   \
        _Pragma("unroll")                                                     \
        for (int j2 = 0; j2 < 4; ++j2) gload16(vb2[j2], v3s + ((c) * 4 + j2) * 2048); \
    } while (0)
#define VCOMP(c, vb2) do {                                                    \
        __builtin_amdgcn_s_setprio(1);                                        \
        _Pragma("unroll")                                                     \
        for (int j2 = 0; j2 < 4; ++j2) {                                      \
            const int kt = kh * 16 + (c) * 4 + j2;                            \
            short8 pa0 = *(const short8*)&P[li][kt * 32 + koff];              \
            short8 pa1 = *(const short8*)&P[16 + li][kt * 32 + koff];         \
            o0 = __builtin_amdgcn_mfma_f32_16x16x32_bf16(pa0, vb2[j2], o0, 0, 0, 0); \
            o1 = __builtin_amdgcn_mfma_f32_16x16x32_bf16(pa1, vb2[j2], o1, 0, 0, 0); \
        }                                                                     \
        __builtin_amdgcn_s_setprio(0);                                        \
    } while (0)
    VISSUE(0, vA); VISSUE(1, vB); VISSUE(2, vC); VISSUE(3, vD);
    WAITV(12); VCOMP(0, vA);
    WAITV(8);  VCOMP(1, vB);
    WAITV(4);  VCOMP(2, vC);
    WAITV(0);  VCOMP(3, vD);
#undef VISSUE
#undef VCOMP

    // ---- merge k-halves
    if (kh == 1) { po[p4][0][lane] = o0; po[p4][1][lane] = o1; }
    __syncthreads();
    if (kh == 0) {
        f32x4 q0 = po[p4][0][lane];
        f32x4 q1 = po[p4][1][lane];
        const int dcol = h * 64 + p4 * 16 + li;
#pragma unroll
        for (int r = 0; r < 4; ++r) {
            const int rw = g * 4 + r;
            const float rs0 = red_sum[0][rw] + red_sum[1][rw] + red_sum[2][rw] + red_sum[3][rw];
            const float rs1 = red_sum[4][rw] + red_sum[5][rw] + red_sum[6][rw] + red_sum[7][rw];
            outb[(size_t)(b * NN + n0 + rw) * NC + dcol]      = f2bf((o0[r] + q0[r]) / rs0);
            outb[(size_t)(b * NN + n0 + 16 + rw) * NC + dcol] = f2bf((o1[r] + q1[r]) / rs1);
        }
    }

    // ---- attn f32 stores: non-temporal
    const float rinv = 1.0f / (red_sum[qs * 4 + 0][li] + red_sum[qs * 4 + 1][li]
                             + red_sum[qs * 4 + 2][li] + red_sum[qs * 4 + 3][li]);
    float* arow = attn_out + (size_t)bh * NN * NN + (size_t)(n0 + qs * 16 + li) * NN
                + ke * 64 + g * 4;
#pragma unroll
    for (int cf = 0; cf < 16; ++cf) {
        f32x4 a4;
#pragma unroll
        for (int r = 0; r < 4; ++r) a4[r] = acc[cf][r] * rinv;
        __builtin_nontemporal_store(a4, (f32x4*)(arow + (cf >> 2) * 256 + (cf & 3) * 16));
    }
}

// ---------- launch ----------
extern "C" void kernel_launch(void* const* d_in, const int* in_sizes, int n_in,
                              void* d_out, int out_size, void* d_ws, size_t ws_size,
                              hipStream_t stream) {
    const float* x      = (const float*)d_in[0];
    const float* mask   = (const float*)d_in[1];
    const float* weight = (const float*)d_in[2];
    const float* qkv_w  = (const float*)d_in[3];
    const float* mu_w   = (const float*)d_in[4];
    const float* mu_b   = (const float*)d_in[5];
    const float* ls_w   = (const float*)d_in[6];
    const float* ls_b   = (const float*)d_in[7];

    char* ws = (char*)d_ws;
    unsigned short* xb   = (unsigned short*)(ws + OFF_XB);
    unsigned short* wq   = (unsigned short*)(ws + OFF_WQ);
    unsigned short* wmu  = (unsigned short*)(ws + OFF_WMU);
    unsigned short* wls  = (unsigned short*)(ws + OFF_WLS);
    unsigned short* qkvb = (unsigned short*)(ws + OFF_QKVB);
    unsigned short* v3   = (unsigned short*)(ws + OFF_V3);
    unsigned short* outb = (unsigned short*)(ws + OFF_OUTB);

    float* out_mu   = (float*)d_out;
    float* out_ls   = out_mu + 3145728;
    float* out_attn = out_mu + 6291456;

    cast_all<<<5376, 256, 0, stream>>>(x, qkv_w, mu_w, ls_w, xb);

    gemm_qkv<<<dim3(TC / 128, 4096 / 128), 256, 0, stream>>>(xb, wq, qkvb);

    pack_v<<<dim3(NN / 64, NB * NH), 256, 0, stream>>>(qkvb, v3);

    attn_kernel<<<dim3(NN / 32, NB * NH), 512, 0, stream>>>(
        qkvb, v3, mask, weight, out_attn, outb);

    gemm_heads<<<dim3(NC / 128, 4096 / 128, 2), 256, 0, stream>>>(
        outb, wmu, wls, mu_b, ls_b, out_mu, out_ls);
}

// Round 12
// 144.728 us; speedup vs baseline: 1.1259x; 1.1259x over previous
//
#include <hip/hip_runtime.h>
#include <hip/hip_bf16.h>

// ---------- types ----------
typedef __attribute__((ext_vector_type(8))) short short8;      // 8 x bf16 (4 VGPR) MFMA frag
typedef __attribute__((ext_vector_type(4))) float f32x4;       // MFMA accumulator
typedef __attribute__((ext_vector_type(4))) unsigned short u16x4;

// ---------- constants ----------
#define NB 4
#define NN 1024
#define NC 768
#define NH 12
#define TC 2304

// workspace byte offsets
#define OFF_XB   0ul
#define OFF_WQ   6291456ul
#define OFF_WMU  (OFF_WQ + 3538944ul)
#define OFF_WLS  (OFF_WMU + 589824ul)
#define OFF_QKVB (OFF_WLS + 589824ul)
#define OFF_V3   (OFF_QKVB + 18874368ul)
#define OFF_OUTB (OFF_V3 + 6291456ul)

__device__ __forceinline__ unsigned short f2bf(float f) {
    unsigned int u = __float_as_uint(f);
    u = (u + 0x7FFFu + ((u >> 16) & 1u)) >> 16;
    return (unsigned short)u;
}

__device__ __forceinline__ void gload_lds16(const unsigned short* g, unsigned short* l) {
    __builtin_amdgcn_global_load_lds(
        (const __attribute__((address_space(1))) unsigned int*)g,
        (__attribute__((address_space(3))) unsigned int*)l, 16, 0, 0);
}

__device__ __forceinline__ void gload16(short8& dst, const unsigned short* p) {
    asm volatile("global_load_dwordx4 %0, %1, off" : "=v"(dst) : "v"(p));
}
#define WAITV(N) do { asm volatile("s_waitcnt vmcnt(" #N ")" ::: "memory"); \
                      __builtin_amdgcn_sched_barrier(0); } while (0)
#define SBAR()   __builtin_amdgcn_sched_barrier(0)

// ---------- fused cast f32 -> bf16 ----------
__global__ void cast_all(const float* __restrict__ x, const float* __restrict__ qkv_w,
                         const float* __restrict__ mu_w, const float* __restrict__ ls_w,
                         unsigned short* __restrict__ dst) {
    int i = blockIdx.x * blockDim.x + threadIdx.x;
    const float* src; int off;
    if (i < 786432)            { src = x;     off = i; }
    else if (i < 1228800)      { src = qkv_w; off = i - 786432; }
    else if (i < 1302528)      { src = mu_w;  off = i - 1228800; }
    else                       { src = ls_w;  off = i - 1302528; }
    f32x4 v = ((const f32x4*)src)[off];
    u16x4 o;
#pragma unroll
    for (int j = 0; j < 4; ++j) o[j] = f2bf(v[j]);
    ((u16x4*)dst)[i] = o;
}

// ---------- shared GEMM body (validated) ----------
template <int EPI>
__device__ __forceinline__ void gemm_body(
    unsigned short* As, unsigned short* Bs,
    const unsigned short* __restrict__ A, const unsigned short* __restrict__ Bm,
    int K, int lda, int ldb, void* __restrict__ Cout, int ldc,
    const float* __restrict__ bias, int row0, int col0)
{
    const int t = threadIdx.x;
    const int lane = t & 63;
    const int wv = t >> 6;
    const int wm = wv >> 1, wn = wv & 1;
    const int li = lane & 15;
    const int koff = (lane >> 4) * 8;

    f32x4 acc[4][4] = {};

    const int tr = t >> 2;
    const int tc = (t & 3) * 8;
    const unsigned short* ag = A + (size_t)(row0 + tr) * lda + tc;
    const unsigned short* bg = Bm + (size_t)(col0 + tr) * ldb + tc;

    for (int kt = 0; kt < K; kt += 32) {
        gload_lds16(ag,            As + t * 8);
        gload_lds16(ag + 64 * lda, As + 2048 + t * 8);
        gload_lds16(bg,            Bs + t * 8);
        gload_lds16(bg + 64 * ldb, Bs + 2048 + t * 8);
        ag += 32; bg += 32;
        __syncthreads();
        short8 af[4], bf[4];
#pragma unroll
        for (int m = 0; m < 4; ++m)
            af[m] = *(const short8*)&As[(wm * 64 + m * 16 + li) * 32 + koff];
#pragma unroll
        for (int n = 0; n < 4; ++n)
            bf[n] = *(const short8*)&Bs[(wn * 64 + n * 16 + li) * 32 + koff];
#pragma unroll
        for (int m = 0; m < 4; ++m)
#pragma unroll
            for (int n = 0; n < 4; ++n)
                acc[m][n] = __builtin_amdgcn_mfma_f32_16x16x32_bf16(af[m], bf[n], acc[m][n], 0, 0, 0);
        __syncthreads();
    }

#pragma unroll
    for (int m = 0; m < 4; ++m) {
        const int row = row0 + wm * 64 + m * 16 + (lane >> 4) * 4;
#pragma unroll
        for (int n = 0; n < 4; ++n) {
            const int col = col0 + wn * 64 + n * 16 + li;
#pragma unroll
            for (int r = 0; r < 4; ++r) {
                if (EPI == 0) {
                    ((unsigned short*)Cout)[(size_t)(row + r) * ldc + col] = f2bf(acc[m][n][r]);
                } else {
                    ((float*)Cout)[(size_t)(row + r) * ldc + col] = acc[m][n][r] + bias[col];
                }
            }
        }
    }
}

__global__ __launch_bounds__(256, 2) void gemm_qkv(
    const unsigned short* __restrict__ A, const unsigned short* __restrict__ Bm,
    unsigned short* __restrict__ C)
{
    __shared__ unsigned short As[128 * 32];
    __shared__ unsigned short Bs[128 * 32];
    const int bid = blockIdx.y * gridDim.x + blockIdx.x;
    const int nwg = gridDim.x * gridDim.y;
    const int swz = (bid & 7) * (nwg >> 3) + (bid >> 3);
    const int row0 = (swz / gridDim.x) * 128;
    const int col0 = (swz % gridDim.x) * 128;
    gemm_body<0>(As, Bs, A, Bm, NC, NC, NC, C, TC, nullptr, row0, col0);
}

__global__ __launch_bounds__(256, 2) void gemm_heads(
    const unsigned short* __restrict__ outb,
    const unsigned short* __restrict__ wmu, const unsigned short* __restrict__ wls,
    const float* __restrict__ mu_b, const float* __restrict__ ls_b,
    float* __restrict__ out_mu, float* __restrict__ out_ls)
{
    __shared__ unsigned short As[128 * 32];
    __shared__ unsigned short Bs[128 * 32];
    const int bid = blockIdx.y * gridDim.x + blockIdx.x;
    const int nwg = gridDim.x * gridDim.y;
    const int swz = (bid & 7) * (nwg >> 3) + (bid >> 3);
    const int row0 = (swz / gridDim.x) * 128;
    const int col0 = (swz % gridDim.x) * 128;
    const int z = blockIdx.z;
    gemm_body<1>(As, Bs, outb + (z ? 384 : 0), z ? wls : wmu, 384, NC, 384,
                 z ? (void*)out_ls : (void*)out_mu, NC, z ? ls_b : mu_b, row0, col0);
}

// ---------- pack V only (frag-order): v3[bh][kt=m/32][d][m%32] ----------
__global__ __launch_bounds__(256, 4) void pack_v(
    const unsigned short* __restrict__ qkvb, unsigned short* __restrict__ v3)
{
    __shared__ unsigned short tile[64][65];
    const int t = threadIdx.x;
    const int bh = blockIdx.y;
    const int b = bh / NH, h = bh % NH;
    const int m0 = blockIdx.x * 64;
#pragma unroll
    for (int i = 0; i < 2; ++i) {
        int lin = i * 256 + t;
        int mr = lin >> 3;
        int dr = (lin & 7) * 8;
        short8 v = *(const short8*)(qkvb + (size_t)(b * NN + m0 + mr) * TC + 1536 + h * 64 + dr);
#pragma unroll
        for (int j = 0; j < 8; ++j) tile[mr][dr + j] = (unsigned short)v[j];
    }
    __syncthreads();
#pragma unroll
    for (int i = 0; i < 2; ++i) {
        int lin = i * 256 + t;
        int dw = lin >> 3;
        int mw = (lin & 7) * 8;
        short8 v;
#pragma unroll
        for (int j = 0; j < 8; ++j) v[j] = (short)tile[mw + j][dw];
        int kt = (m0 + mw) >> 5;
        int mm = mw & 31;
        *(short8*)(v3 + ((size_t)(bh * 32 + kt) * 64 + dw) * 32 + mm) = v;
    }
}

// ---------- fused attention: QBLK=16, low-LDS low-VGPR, high-TLP ----------
// grid (64, 48); block 512 = 8 waves. QK: per 128-key chunk, wave wv owns keys
// [wv*16, wv*16+16) -> acc[8] (one frag per chunk). LDS: K dbuf 2x16KB overlaid
// by P[16][1032] (33KB). Target 3 blocks/CU via __launch_bounds__(512,6).
__global__ __launch_bounds__(512, 6) void attn_kernel(
    const unsigned short* __restrict__ qkvb, const unsigned short* __restrict__ v3,
    const float* __restrict__ mask, const float* __restrict__ weight,
    float* __restrict__ attn_out, unsigned short* __restrict__ outb)
{
    __shared__ __align__(16) char smem[33024];   // K dbuf 2x16KB | later P[16][1032]
    __shared__ f32x4 po[4][64];                  // PV k-half exchange
    __shared__ float red_max[8][16];
    __shared__ float red_sum[8][16];

    const int t = threadIdx.x;
    const int lane = t & 63;
    const int wv = t >> 6;                 // 0..7
    const int li = lane & 15;
    const int g = lane >> 4;
    const int koff = g * 8;
    const int bh = blockIdx.y;
    const int b = bh / NH, h = bh % NH;
    const int n0 = blockIdx.x * 16;

    unsigned short* sm = (unsigned short*)smem;

    // q frags (B-operand): col = li -> q-row n0+li (same for all waves)
    const unsigned short* qp = qkvb + (size_t)(b * NN + n0 + li) * TC + h * 64 + koff;
    short8 qf0 = *(const short8*)qp;
    short8 qf1 = *(const short8*)(qp + 32);

    const float* mrow = mask + (size_t)b * NN * NN + (size_t)(n0 + li) * NN + wv * 16 + g * 4;
    const unsigned short* kgbase = qkvb + (size_t)(b * NN) * TC + 768 + h * 64;

    f32x4 acc[8];
    f32x4 mk[2];

    // cooperative stage of 128-key chunk ck into buf ck&1 (2 gload_lds/thread, 1KB/wave-instr)
    // LDS dest: uniform base + lane*16. Source 16B-slot pre-XOR'd (both-sides swizzle).
    auto stage = [&](int ck) {
#pragma unroll
        for (int i = 0; i < 2; ++i) {
            int m = wv * 16 + i * 8 + (lane >> 3);        // key within chunk 0..127
            int sl = (lane & 7) ^ (m & 7);                // swizzled 16B slot in source
            const unsigned short* src = kgbase + (size_t)(ck * 128 + m) * TC + sl * 8;
            unsigned short* dst = sm + (ck & 1) * 8192 + wv * 1024 + i * 512 + lane * 8;
            gload_lds16(src, dst);
        }
    };

    stage(0);
    mk[0] = *(const f32x4*)(mrow);
    __syncthreads();                        // drains stage(0)+mk[0]

#pragma unroll
    for (int ck = 0; ck < 8; ++ck) {
        if (ck < 7) {
            stage(ck + 1);
            mk[(ck + 1) & 1] = *(const f32x4*)(mrow + (ck + 1) * 128);
        }
        const unsigned short* kbuf = sm + (ck & 1) * 8192;
        // wave's frag: rows = keys wv*16+li of this chunk
        short8 kf0 = *(const short8*)&kbuf[(wv * 16 + li) * 64 + ((g ^ (li & 7)) * 8)];
        short8 kf1 = *(const short8*)&kbuf[(wv * 16 + li) * 64 + (((g + 4) ^ (li & 7)) * 8)];
        f32x4 ci = mk[ck & 1] * 96.0f;      // mask as C-in (scale=1/96 exact)
        ci = __builtin_amdgcn_mfma_f32_16x16x32_bf16(kf0, qf0, ci, 0, 0, 0);
        ci = __builtin_amdgcn_mfma_f32_16x16x32_bf16(kf1, qf1, ci, 0, 0, 0);
        acc[ck] = ci;
        __syncthreads();                    // staging of ck+1 complete; buf reuse safe
    }

    // ---- row max over this wave's 128 keys (acc = s*96; monotone)
    const float scale = 1.0f / 96.0f;
    float rmax = -1e30f;
#pragma unroll
    for (int cf = 0; cf < 8; ++cf) {
#pragma unroll
        for (int r = 0; r < 4; ++r) rmax = fmaxf(rmax, acc[cf][r]);
    }
    rmax = fmaxf(rmax, __shfl_xor(rmax, 16, 64));
    rmax = fmaxf(rmax, __shfl_xor(rmax, 32, 64));
    if (lane < 16) red_max[wv][lane] = rmax;
    __syncthreads();                        // all waves done with K LDS too
    {
        float m01 = fmaxf(red_max[0][li], red_max[1][li]);
        float m23 = fmaxf(red_max[2][li], red_max[3][li]);
        float m45 = fmaxf(red_max[4][li], red_max[5][li]);
        float m67 = fmaxf(red_max[6][li], red_max[7][li]);
        rmax = fmaxf(fmaxf(m01, m23), fmaxf(m45, m67)) * scale;
    }

    // ---- p = exp(s-max)*w; stage bf16 p into P (overlays K bufs); weighted row sum
    // weight reloaded per frag (no live w4 register block)
    unsigned short (*P)[1032] = (unsigned short(*)[1032])smem;
    const float* wbase = weight + b * NN + wv * 16 + g * 4;
    float rsum = 0.f;
#pragma unroll
    for (int cf = 0; cf < 8; ++cf) {
        f32x4 wcf = *(const f32x4*)(wbase + cf * 128);
        u16x4 pb;
#pragma unroll
        for (int r = 0; r < 4; ++r) {
            float p = __expf(acc[cf][r] * scale - rmax) * (wcf[r] + 1e-10f);
            acc[cf][r] = p;
            rsum += p;
            pb[r] = f2bf(p);
        }
        *(u16x4*)&P[li][cf * 128 + wv * 16 + g * 4] = pb;
    }
    rsum += __shfl_xor(rsum, 16, 64);
    rsum += __shfl_xor(rsum, 32, 64);
    if (lane < 16) red_sum[wv][lane] = rsum;
    __syncthreads();                        // P complete + red_sum ready

    // ---- attn f32 stores FIRST (acc dies here; drain folded into PV waits)
    const float rinv = 1.0f / (red_sum[0][li] + red_sum[1][li] + red_sum[2][li]
                             + red_sum[3][li] + red_sum[4][li] + red_sum[5][li]
                             + red_sum[6][li] + red_sum[7][li]);
    float* arow = attn_out + (size_t)bh * NN * NN + (size_t)(n0 + li) * NN + wv * 16 + g * 4;
#pragma unroll
    for (int cf = 0; cf < 8; ++cf) {
        f32x4 a4;
#pragma unroll
        for (int r = 0; r < 4; ++r) a4[r] = acc[cf][r] * rinv;
        __builtin_nontemporal_store(a4, (f32x4*)(arow + cf * 128));
    }

    // ---- PV: wave (kh = wv>>2, p4 = wv&3): keys [kh*512,+512), d-cols [p4*16,+16).
    // vmcnt ledger: 8 stores (S) then V0(4), V1(4): WAITV(4) => S+V0 done.
    const int kh = wv >> 2, p4 = wv & 3;
    f32x4 o = {};
    const unsigned short* v3s = v3 + (size_t)bh * 65536 + (size_t)(kh * 16) * 2048
                              + p4 * 512 + li * 32 + g * 8;
    short8 vA[4], vB[4];
#define VISSUE(c, vb2) do {                                                   \
        _Pragma("unroll")                                                     \
        for (int j2 = 0; j2 < 4; ++j2) gload16(vb2[j2], v3s + ((c) * 4 + j2) * 2048); \
    } while (0)
#define VCOMP(c, vb2) do {                                                    \
        __builtin_amdgcn_s_setprio(1);                                        \
        _Pragma("unroll")                                                     \
        for (int j2 = 0; j2 < 4; ++j2) {                                      \
            const int kt = kh * 16 + (c) * 4 + j2;                            \
            short8 pa = *(const short8*)&P[li][kt * 32 + koff];               \
            o = __builtin_amdgcn_mfma_f32_16x16x32_bf16(pa, vb2[j2], o, 0, 0, 0); \
        }                                                                     \
        __builtin_amdgcn_s_setprio(0);                                        \
    } while (0)
    VISSUE(0, vA);
    VISSUE(1, vB);
    WAITV(4);  VCOMP(0, vA); SBAR(); VISSUE(2, vA);
    WAITV(4);  VCOMP(1, vB); SBAR(); VISSUE(3, vB);
    WAITV(4);  VCOMP(2, vA);
    WAITV(0);  VCOMP(3, vB);
#undef VISSUE
#undef VCOMP

    // ---- merge k-halves: waves 4-7 publish, waves 0-3 add + store outb
    if (kh == 1) po[p4][lane] = o;
    __syncthreads();
    if (kh == 0) {
        f32x4 oo = po[p4][lane];
        const int dcol = h * 64 + p4 * 16 + li;
#pragma unroll
        for (int r = 0; r < 4; ++r) {
            const int row = g * 4 + r;
            const float rs = red_sum[0][row] + red_sum[1][row] + red_sum[2][row]
                           + red_sum[3][row] + red_sum[4][row] + red_sum[5][row]
                           + red_sum[6][row] + red_sum[7][row];
            outb[(size_t)(b * NN + n0 + row) * NC + dcol] = f2bf((o[r] + oo[r]) / rs);
        }
    }
}

// ---------- launch ----------
extern "C" void kernel_launch(void* const* d_in, const int* in_sizes, int n_in,
                              void* d_out, int out_size, void* d_ws, size_t ws_size,
                              hipStream_t stream) {
    const float* x      = (const float*)d_in[0];
    const float* mask   = (const float*)d_in[1];
    const float* weight = (const float*)d_in[2];
    const float* qkv_w  = (const float*)d_in[3];
    const float* mu_w   = (const float*)d_in[4];
    const float* mu_b   = (const float*)d_in[5];
    const float* ls_w   = (const float*)d_in[6];
    const float* ls_b   = (const float*)d_in[7];

    char* ws = (char*)d_ws;
    unsigned short* xb   = (unsigned short*)(ws + OFF_XB);
    unsigned short* wq   = (unsigned short*)(ws + OFF_WQ);
    unsigned short* wmu  = (unsigned short*)(ws + OFF_WMU);
    unsigned short* wls  = (unsigned short*)(ws + OFF_WLS);
    unsigned short* qkvb = (unsigned short*)(ws + OFF_QKVB);
    unsigned short* v3   = (unsigned short*)(ws + OFF_V3);
    unsigned short* outb = (unsigned short*)(ws + OFF_OUTB);

    float* out_mu   = (float*)d_out;
    float* out_ls   = out_mu + 3145728;
    float* out_attn = out_mu + 6291456;

    cast_all<<<5376, 256, 0, stream>>>(x, qkv_w, mu_w, ls_w, xb);

    gemm_qkv<<<dim3(TC / 128, 4096 / 128), 256, 0, stream>>>(xb, wq, qkvb);

    pack_v<<<dim3(NN / 64, NB * NH), 256, 0, stream>>>(qkvb, v3);

    attn_kernel<<<dim3(NN / 16, NB * NH), 512, 0, stream>>>(
        qkvb, v3, mask, weight, out_attn, outb);

    gemm_heads<<<dim3(NC / 128, 4096 / 128, 2), 256, 0, stream>>>(
        outb, wmu, wls, mu_b, ls_b, out_mu, out_ls);
}